// Round 6
// baseline (1286.937 us; speedup 1.0000x reference)
//
#include <hip/hip_runtime.h>
#include <stdint.h>

#define NCODES 8192
#define NROWS 1024    // B*NCQ

// workspace offsets (in floats)
#define OFF_LOGITS 0ll
#define OFF_X      8388608ll
#define OFF_QKV    9437184ll
#define OFF_ATTN   12582912ll
#define OFF_FLAT   13631488ll
#define OFF_CSQ    14418944ll
// reuse: cbbf (bf16 codebook, 12 MB) overlays qkv (dead after layer 2);
//        fbf  (bf16 flat, 1.5 MB)   overlays attno (dead after layer 2);
//        approx (2*dot, fp32)       overlays logits region.

// ---------------- Threefry2x32, key = (0, 42)  (jax.random.key(42)) ----------------
__device__ __forceinline__ uint32_t rotl32(uint32_t x, int r) { return (x << r) | (x >> (32 - r)); }

__device__ __forceinline__ void tf2x32_key42(uint32_t x0, uint32_t x1, uint32_t& o0, uint32_t& o1) {
  const uint32_t k0 = 0u, k1 = 42u;
  const uint32_t k2 = k0 ^ k1 ^ 0x1BD11BDAu;
  x0 += k0; x1 += k1;
  x0 += x1; x1 = rotl32(x1,13); x1 ^= x0;
  x0 += x1; x1 = rotl32(x1,15); x1 ^= x0;
  x0 += x1; x1 = rotl32(x1,26); x1 ^= x0;
  x0 += x1; x1 = rotl32(x1, 6); x1 ^= x0;
  x0 += k1; x1 += k2 + 1u;
  x0 += x1; x1 = rotl32(x1,17); x1 ^= x0;
  x0 += x1; x1 = rotl32(x1,29); x1 ^= x0;
  x0 += x1; x1 = rotl32(x1,16); x1 ^= x0;
  x0 += x1; x1 = rotl32(x1,24); x1 ^= x0;
  x0 += k2; x1 += k0 + 2u;
  x0 += x1; x1 = rotl32(x1,13); x1 ^= x0;
  x0 += x1; x1 = rotl32(x1,15); x1 ^= x0;
  x0 += x1; x1 = rotl32(x1,26); x1 ^= x0;
  x0 += x1; x1 = rotl32(x1, 6); x1 ^= x0;
  x0 += k0; x1 += k1 + 3u;
  x0 += x1; x1 = rotl32(x1,17); x1 ^= x0;
  x0 += x1; x1 = rotl32(x1,29); x1 ^= x0;
  x0 += x1; x1 = rotl32(x1,16); x1 ^= x0;
  x0 += x1; x1 = rotl32(x1,24); x1 ^= x0;
  x0 += k1; x1 += k2 + 4u;
  x0 += x1; x1 = rotl32(x1,13); x1 ^= x0;
  x0 += x1; x1 = rotl32(x1,15); x1 ^= x0;
  x0 += x1; x1 = rotl32(x1,26); x1 ^= x0;
  x0 += x1; x1 = rotl32(x1, 6); x1 ^= x0;
  x0 += k2; x1 += k0 + 5u;
  o0 = x0; o1 = x1;
}

__device__ __forceinline__ float gumbel_at(uint32_t idx) {
  uint32_t y0, y1;
  tf2x32_key42(0u, idx, y0, y1);
  uint32_t bits = y0 ^ y1;
  float f = __uint_as_float((bits >> 9) | 0x3f800000u) - 1.0f;
  float u = fmaxf(f, 1.17549435e-38f);
  return -logf(-logf(u));
}

// ---------------- K0: x = xcq @ fc_in_w.T + b ; also copy xcq -> out (output 1) ------
// Split-K, no LDS, no barriers, max TLP (G1/G11): 16 lanes per token, each lane
// streams 12 interleaved float4 of the token row (coalesced 256B per 16-lane group),
// copies them to out, and FMAs into acc[32]. __shfl_xor width-16 tree reduce, then
// predicated static-index writes (rule #20: no runtime-indexed register arrays).
// W working set per i-step = 32 rows x 256B = 8KB -> L1-resident; 96KB total -> L2.
// Grid 2048x256 = 8192 waves (vs 512 before) -> latency hidden by occupancy.
__global__ __launch_bounds__(256, 4) void k_fcin(const float* __restrict__ xcq,
                                                 const float* __restrict__ W,
                                                 const float* __restrict__ b,
                                                 float* __restrict__ x,
                                                 float* __restrict__ outcopy) {
  int t = threadIdx.x;
  int sub = t & 15;
  long tok = (long)blockIdx.x * 16 + (t >> 4);
  const float4* xcq4 = (const float4*)xcq;
  const float4* W4 = (const float4*)W;
  float4* out4 = (float4*)outcopy;
  float acc[32];
  #pragma unroll
  for (int c = 0; c < 32; c++) acc[c] = 0.f;
  #pragma unroll
  for (int i = 0; i < 12; i++) {
    int j4 = sub + 16 * i;
    float4 v = xcq4[tok * 192 + j4];
    out4[tok * 192 + j4] = v;
    #pragma unroll
    for (int c = 0; c < 32; c++) {
      float4 wv = W4[c * 192 + j4];
      acc[c] += v.x * wv.x + v.y * wv.y + v.z * wv.z + v.w * wv.w;
    }
  }
  // tree-reduce across the 16-lane group (4 tokens per wave, groups don't straddle)
  #pragma unroll
  for (int c = 0; c < 32; c++) {
    #pragma unroll
    for (int off = 1; off <= 8; off <<= 1)
      acc[c] += __shfl_xor(acc[c], off, 16);
  }
  // write x: lane sub==s8 writes float4 chunk s8 (all indices compile-time)
  float4* x4 = (float4*)x;
  #pragma unroll
  for (int s8 = 0; s8 < 8; s8++) {
    if (sub == s8) {
      float4 o;
      o.x = acc[4*s8+0] + b[4*s8+0];
      o.y = acc[4*s8+1] + b[4*s8+1];
      o.z = acc[4*s8+2] + b[4*s8+2];
      o.w = acc[4*s8+3] + b[4*s8+3];
      x4[tok * 8 + s8] = o;
    }
  }
}

// ---------------- K1: qkv = x @ Win.T + bin  (per-token, W wave-uniform) ----------------
__global__ __launch_bounds__(64) void k_qkv(const float* __restrict__ x,
                                            const float* __restrict__ W,
                                            const float* __restrict__ b,
                                            float* __restrict__ qkv) {
  long token = (long)blockIdx.x * 64 + threadIdx.x;
  const float4* x4 = (const float4*)x;
  const float4* W4 = (const float4*)W;
  float4* q4 = (float4*)qkv;
  float4 xr[8];
  #pragma unroll
  for (int j4 = 0; j4 < 8; j4++) xr[j4] = x4[token * 8 + j4];
  #pragma unroll
  for (int c4 = 0; c4 < 24; c4++) {
    float s[4];
    #pragma unroll
    for (int q = 0; q < 4; q++) {
      int c = c4 * 4 + q;
      float acc = 0.f;
      #pragma unroll
      for (int j4 = 0; j4 < 8; j4++) {
        float4 wv = W4[c * 8 + j4];   // uniform
        acc += xr[j4].x * wv.x + xr[j4].y * wv.y + xr[j4].z * wv.z + xr[j4].w * wv.w;
      }
      s[q] = acc + b[c];
    }
    q4[token * 24 + c4] = make_float4(s[0], s[1], s[2], s[3]);
  }
}

// ---------------- K2: attention, one (batch, head) per block, 2 queries/thread ----------
__global__ __launch_bounds__(256) void k_attn(const float* __restrict__ qkv,
                                              const int* __restrict__ amask,
                                              float* __restrict__ attno) {
  int z = blockIdx.x;              // 0..255
  int b = z >> 2;
  int h = z & 3;
  __shared__ float4 ks4[512 * 2];
  __shared__ float4 vs4[512 * 2];
  __shared__ float inval[512];
  int t = threadIdx.x;
  long qb4 = (long)b * 512 * 24;
  const float4* qkv4 = (const float4*)qkv;
  #pragma unroll
  for (int p = 0; p < 4; p++) {
    int f = t + 256 * p;             // token*2 + half4
    int tok = f >> 1, hf = f & 1;
    ks4[f] = qkv4[qb4 + (long)tok * 24 + 8 + h * 2 + hf];
    vs4[f] = qkv4[qb4 + (long)tok * 24 + 16 + h * 2 + hf];
  }
  #pragma unroll
  for (int p = 0; p < 2; p++) {
    int l = t + 256 * p;
    inval[l] = (l < 16 || amask[b * 496 + (l - 16)] != 0) ? 0.f : 1.f;
  }
  __syncthreads();
  const float scale = 0.35355339059327373f;
  float4 qa0 = qkv4[qb4 + (long)t * 24 + h * 2];
  float4 qb0 = qkv4[qb4 + (long)t * 24 + h * 2 + 1];
  float4 qa1 = qkv4[qb4 + (long)(t + 256) * 24 + h * 2];
  float4 qb1 = qkv4[qb4 + (long)(t + 256) * 24 + h * 2 + 1];
  float m0 = -3.4e38f, m1 = -3.4e38f;
  #pragma unroll 2
  for (int lk = 0; lk < 512; lk++) {
    float4 ka = ks4[lk * 2], kb = ks4[lk * 2 + 1];
    float iv = inval[lk];
    float s0 = qa0.x*ka.x + qa0.y*ka.y + qa0.z*ka.z + qa0.w*ka.w
             + qb0.x*kb.x + qb0.y*kb.y + qb0.z*kb.z + qb0.w*kb.w;
    s0 *= scale;
    s0 = iv != 0.f ? -1e9f : s0;
    m0 = fmaxf(m0, s0);
    float s1 = qa1.x*ka.x + qa1.y*ka.y + qa1.z*ka.z + qa1.w*ka.w
             + qb1.x*kb.x + qb1.y*kb.y + qb1.z*kb.z + qb1.w*kb.w;
    s1 *= scale;
    s1 = iv != 0.f ? -1e9f : s1;
    m1 = fmaxf(m1, s1);
  }
  float d0 = 0.f, d1 = 0.f;
  float4 o00 = make_float4(0,0,0,0), o01 = make_float4(0,0,0,0);
  float4 o10 = make_float4(0,0,0,0), o11 = make_float4(0,0,0,0);
  #pragma unroll 2
  for (int lk = 0; lk < 512; lk++) {
    float4 ka = ks4[lk * 2], kb = ks4[lk * 2 + 1];
    float4 va = vs4[lk * 2], vb = vs4[lk * 2 + 1];
    float iv = inval[lk];
    float s0 = qa0.x*ka.x + qa0.y*ka.y + qa0.z*ka.z + qa0.w*ka.w
             + qb0.x*kb.x + qb0.y*kb.y + qb0.z*kb.z + qb0.w*kb.w;
    s0 *= scale;
    s0 = iv != 0.f ? -1e9f : s0;
    float p0 = expf(s0 - m0);
    d0 += p0;
    o00.x += p0 * va.x; o00.y += p0 * va.y; o00.z += p0 * va.z; o00.w += p0 * va.w;
    o01.x += p0 * vb.x; o01.y += p0 * vb.y; o01.z += p0 * vb.z; o01.w += p0 * vb.w;
    float s1 = qa1.x*ka.x + qa1.y*ka.y + qa1.z*ka.z + qa1.w*ka.w
             + qb1.x*kb.x + qb1.y*kb.y + qb1.z*kb.z + qb1.w*kb.w;
    s1 *= scale;
    s1 = iv != 0.f ? -1e9f : s1;
    float p1 = expf(s1 - m1);
    d1 += p1;
    o10.x += p1 * va.x; o10.y += p1 * va.y; o10.z += p1 * va.z; o10.w += p1 * va.w;
    o11.x += p1 * vb.x; o11.y += p1 * vb.y; o11.z += p1 * vb.z; o11.w += p1 * vb.w;
  }
  float4* a4 = (float4*)attno;
  float inv0 = 1.f / d0;
  long ob0 = ((long)b * 512 + t) * 8 + h * 2;
  a4[ob0]     = make_float4(o00.x*inv0, o00.y*inv0, o00.z*inv0, o00.w*inv0);
  a4[ob0 + 1] = make_float4(o01.x*inv0, o01.y*inv0, o01.z*inv0, o01.w*inv0);
  float inv1 = 1.f / d1;
  long ob1 = ((long)b * 512 + t + 256) * 8 + h * 2;
  a4[ob1]     = make_float4(o10.x*inv1, o10.y*inv1, o10.z*inv1, o10.w*inv1);
  a4[ob1 + 1] = make_float4(o11.x*inv1, o11.y*inv1, o11.z*inv1, o11.w*inv1);
}

// ---------------- K3: x = LN1(x + attno @ Wout.T + bout)  (per-token) ----------------
__global__ __launch_bounds__(64) void k_oproj_ln(const float* __restrict__ attno,
                                                 const float* __restrict__ W,
                                                 const float* __restrict__ b,
                                                 const float* __restrict__ g,
                                                 const float* __restrict__ beta,
                                                 float* __restrict__ x) {
  long token = (long)blockIdx.x * 64 + threadIdx.x;
  const float4* a4 = (const float4*)attno;
  const float4* x4 = (const float4*)x;
  const float4* W4 = (const float4*)W;
  float4 orow[8];
  float xr[32];
  #pragma unroll
  for (int j4 = 0; j4 < 8; j4++) {
    orow[j4] = a4[token * 8 + j4];
    float4 v = x4[token * 8 + j4];
    xr[j4*4] = v.x; xr[j4*4+1] = v.y; xr[j4*4+2] = v.z; xr[j4*4+3] = v.w;
  }
  float v[32];
  #pragma unroll
  for (int c = 0; c < 32; c++) {
    float acc = 0.f;
    #pragma unroll
    for (int j4 = 0; j4 < 8; j4++) {
      float4 wv = W4[c * 8 + j4];   // uniform
      acc += orow[j4].x * wv.x + orow[j4].y * wv.y + orow[j4].z * wv.z + orow[j4].w * wv.w;
    }
    v[c] = acc + b[c] + xr[c];
  }
  float mu = 0.f;
  #pragma unroll
  for (int c = 0; c < 32; c++) mu += v[c];
  mu *= 0.03125f;
  float var = 0.f;
  #pragma unroll
  for (int c = 0; c < 32; c++) { float d = v[c] - mu; var += d * d; }
  var *= 0.03125f;
  float inv = 1.f / sqrtf(var + 1e-5f);
  float4* xo4 = (float4*)x;
  #pragma unroll
  for (int j4 = 0; j4 < 8; j4++) {
    float4 o;
    o.x = g[j4*4]   * (v[j4*4]   - mu) * inv + beta[j4*4];
    o.y = g[j4*4+1] * (v[j4*4+1] - mu) * inv + beta[j4*4+1];
    o.z = g[j4*4+2] * (v[j4*4+2] - mu) * inv + beta[j4*4+2];
    o.w = g[j4*4+3] * (v[j4*4+3] - mu) * inv + beta[j4*4+3];
    xo4[token * 8 + j4] = o;
  }
}

// ---------------- K4: x = LN2(x + relu(x@W1.T+b1)@W2.T + b2)  (per-token) ----------------
__global__ __launch_bounds__(64) void k_ffn_ln(const float* __restrict__ x,
                                               const float* __restrict__ W1,
                                               const float* __restrict__ b1,
                                               const float* __restrict__ W2,
                                               const float* __restrict__ b2,
                                               const float* __restrict__ g,
                                               const float* __restrict__ beta,
                                               float* __restrict__ xout) {
  long token = (long)blockIdx.x * 64 + threadIdx.x;
  const float4* x4 = (const float4*)x;
  const float4* W14 = (const float4*)W1;
  const float4* W24 = (const float4*)W2;
  float xr[32];
  #pragma unroll
  for (int j4 = 0; j4 < 8; j4++) {
    float4 v = x4[token * 8 + j4];
    xr[j4*4] = v.x; xr[j4*4+1] = v.y; xr[j4*4+2] = v.z; xr[j4*4+3] = v.w;
  }
  float h[64];
  #pragma unroll
  for (int c = 0; c < 64; c++) {
    float acc = 0.f;
    #pragma unroll
    for (int j4 = 0; j4 < 8; j4++) {
      float4 wv = W14[c * 8 + j4];   // uniform
      acc += xr[j4*4] * wv.x + xr[j4*4+1] * wv.y + xr[j4*4+2] * wv.z + xr[j4*4+3] * wv.w;
    }
    h[c] = fmaxf(acc + b1[c], 0.f);
  }
  float v[32];
  #pragma unroll
  for (int c = 0; c < 32; c++) {
    float acc = 0.f;
    #pragma unroll
    for (int j4 = 0; j4 < 16; j4++) {
      float4 wv = W24[c * 16 + j4];   // uniform
      acc += h[j4*4] * wv.x + h[j4*4+1] * wv.y + h[j4*4+2] * wv.z + h[j4*4+3] * wv.w;
    }
    v[c] = acc + b2[c] + xr[c];
  }
  float mu = 0.f;
  #pragma unroll
  for (int c = 0; c < 32; c++) mu += v[c];
  mu *= 0.03125f;
  float var = 0.f;
  #pragma unroll
  for (int c = 0; c < 32; c++) { float d = v[c] - mu; var += d * d; }
  var *= 0.03125f;
  float inv = 1.f / sqrtf(var + 1e-5f);
  float4* xo4 = (float4*)xout;
  #pragma unroll
  for (int j4 = 0; j4 < 8; j4++) {
    float4 o;
    o.x = g[j4*4]   * (v[j4*4]   - mu) * inv + beta[j4*4];
    o.y = g[j4*4+1] * (v[j4*4+1] - mu) * inv + beta[j4*4+1];
    o.z = g[j4*4+2] * (v[j4*4+2] - mu) * inv + beta[j4*4+2];
    o.w = g[j4*4+3] * (v[j4*4+3] - mu) * inv + beta[j4*4+3];
    xo4[token * 8 + j4] = o;
  }
}

// ---------------- K5: flat = x[:, :16] @ fc_out_w.T + b  (one flat row per block) -------
// Grid 1024 (was 64): full-device parallelism; x row is thread-invariant -> s_loads.
// Same fmaf order per output as before.
__global__ __launch_bounds__(256) void k_fcout(const float* __restrict__ x,
                                               const float* __restrict__ W,
                                               const float* __restrict__ b,
                                               float* __restrict__ flat) {
  int n = blockIdx.x;           // 0..1023 flat row
  int bb = n >> 4, r = n & 15;
  long xrow = (long)bb * 512 + r;
  const float4* x4 = (const float4*)x;
  float4 xr[8];
  #pragma unroll
  for (int j4 = 0; j4 < 8; j4++) xr[j4] = x4[xrow * 8 + j4];   // uniform -> s_load
  int t = threadIdx.x;
  #pragma unroll
  for (int i = 0; i < 3; i++) {
    int e = t + 256 * i;
    const float4* w4 = (const float4*)(W + e * 32);
    float s = 0.f;
    #pragma unroll
    for (int j4 = 0; j4 < 8; j4++) {
      float4 wv = w4[j4];
      s += xr[j4].x * wv.x + xr[j4].y * wv.y + xr[j4].z * wv.z + xr[j4].w * wv.w;
    }
    flat[(long)n * 768 + e] = s + b[e];
  }
}

// ---------------- K6: cb_sq[k] = sum(codebook[k]^2) ----------------
__global__ __launch_bounds__(256) void k_cbsq(const float* __restrict__ cb,
                                              float* __restrict__ cb_sq) {
  int w = threadIdx.x >> 6, lane = threadIdx.x & 63;
  int k = blockIdx.x * 4 + w;
  const float* row = cb + (long)k * 768;
  float s = 0.f;
  #pragma unroll
  for (int i = 0; i < 12; i++) { float v = row[lane + 64 * i]; s += v * v; }
  #pragma unroll
  for (int off = 32; off >= 1; off >>= 1) s += __shfl_xor(s, off);
  if (lane == 0) cb_sq[k] = s;
}

// ---------------- K6b: fp32 -> bf16 (RNE), vectorized float4 -> ushort4 --------------
__device__ __forceinline__ ushort f2bf(float x) {
  uint32_t u = __float_as_uint(x);
  uint32_t r = (u + 0x7fffu + ((u >> 16) & 1u)) >> 16;
  return (ushort)r;
}

__global__ __launch_bounds__(256) void k_tobf16(const float* __restrict__ src,
                                                ushort* __restrict__ dst, long n4) {
  long i = (long)blockIdx.x * 256 + threadIdx.x;
  if (i >= n4) return;
  float4 v = ((const float4*)src)[i];
  ushort4 o;
  o.x = f2bf(v.x); o.y = f2bf(v.y); o.z = f2bf(v.z); o.w = f2bf(v.w);
  ((ushort4*)dst)[i] = o;
}

// ---------------- K7: approx[n,k] = 2 * <flat_bf16[n], cb_bf16[k]>  via MFMA ----------
typedef __attribute__((ext_vector_type(8))) short bf16x8;
typedef __attribute__((ext_vector_type(4))) float f32x4;

__global__ __launch_bounds__(256, 2) void k_logits_mfma(const ushort* __restrict__ fbf,
                                                        const ushort* __restrict__ cbbf,
                                                        float* __restrict__ approx) {
  __shared__ __align__(16) short As[128 * 64];
  __shared__ __align__(16) short Bs[128 * 64];
  int t = threadIdx.x;
  int mb = blockIdx.x & 7;        // 8 row-blocks of 128 (M=1024)
  int nb = blockIdx.x >> 3;       // 64 col-blocks of 128 (N=8192)
  int w = t >> 6, lane = t & 63;
  int wr = w >> 1, wc = w & 1;    // 2x2 wave grid, 64x64 per wave

  f32x4 zero; zero.x = 0.f; zero.y = 0.f; zero.z = 0.f; zero.w = 0.f;
  f32x4 acc[4][4];
  #pragma unroll
  for (int i = 0; i < 4; i++)
    #pragma unroll
    for (int j = 0; j < 4; j++) acc[i][j] = zero;

  for (int kt = 0; kt < 12; kt++) {
    int kc = kt * 64;
    bf16x8 ra[4], rb[4];
    #pragma unroll
    for (int p = 0; p < 4; p++) {
      int li = p * 256 + t;
      int row = li >> 3, s = li & 7;
      ra[p] = *(const bf16x8*)(fbf + (long)(mb * 128 + row) * 768 + kc + s * 8);
      rb[p] = *(const bf16x8*)(cbbf + (long)(nb * 128 + row) * 768 + kc + s * 8);
    }
    __syncthreads();
    #pragma unroll
    for (int p = 0; p < 4; p++) {
      int li = p * 256 + t;
      int row = li >> 3, s = li & 7, ss = s ^ (row & 7);
      *(bf16x8*)(As + row * 64 + ss * 8) = ra[p];
      *(bf16x8*)(Bs + row * 64 + ss * 8) = rb[p];
    }
    __syncthreads();
    #pragma unroll
    for (int ks = 0; ks < 2; ks++) {
      int slot = ks * 4 + (lane >> 4);
      bf16x8 a[4], b[4];
      #pragma unroll
      for (int i = 0; i < 4; i++) {
        int rowa = wr * 64 + i * 16 + (lane & 15);
        a[i] = *(const bf16x8*)(As + rowa * 64 + (slot ^ (rowa & 7)) * 8);
        int rowb = wc * 64 + i * 16 + (lane & 15);
        b[i] = *(const bf16x8*)(Bs + rowb * 64 + (slot ^ (rowb & 7)) * 8);
      }
      #pragma unroll
      for (int i = 0; i < 4; i++)
        #pragma unroll
        for (int j = 0; j < 4; j++)
          acc[i][j] = __builtin_amdgcn_mfma_f32_16x16x32_bf16(a[i], b[j], acc[i][j], 0, 0, 0);
    }
  }
  long rbase = (long)mb * 128 + wr * 64 + (lane >> 4) * 4;
  int cbase = nb * 128 + wc * 64 + (lane & 15);
  #pragma unroll
  for (int i = 0; i < 4; i++) {
    #pragma unroll
    for (int j = 0; j < 4; j++) {
      f32x4 v = acc[i][j];
      long r0 = rbase + i * 16;
      int c = cbase + j * 16;
      approx[(r0 + 0) * 8192 + c] = 2.f * v.x;
      approx[(r0 + 1) * 8192 + c] = 2.f * v.y;
      approx[(r0 + 2) * 8192 + c] = 2.f * v.z;
      approx[(r0 + 3) * 8192 + c] = 2.f * v.w;
    }
  }
}

// ---------------- K8: gumbel-max sampling with approx-threshold + exact rescue --------
__global__ __launch_bounds__(256) void k_sample(const float* __restrict__ approx,
                                                const float* __restrict__ cb,
                                                const float* __restrict__ csq,
                                                const float* __restrict__ flat,
                                                float* __restrict__ out0) {
  int n = blockIdx.x, t = threadIdx.x;
  const float* arow = approx + (long)n * 8192;
  __shared__ float s_max[4];
  __shared__ int s_cnt;
  __shared__ int cand[8192];
  __shared__ float fs[768];
  __shared__ float redv[64];
  __shared__ int redi[64];
  __shared__ int draws[16];
  if (t < 192) ((float4*)fs)[t] = ((const float4*)(flat + (long)n * 768))[t];
  float va[32];
  float m = -3.4e38f;
  #pragma unroll
  for (int i = 0; i < 32; i++) { va[i] = arow[t + 256 * i]; m = fmaxf(m, va[i]); }
  #pragma unroll
  for (int off = 32; off >= 1; off >>= 1) m = fmaxf(m, __shfl_xor(m, off));
  if ((t & 63) == 0) s_max[t >> 6] = m;
  if (t == 0) s_cnt = 0;
  __syncthreads();
  float rowmax = fmaxf(fmaxf(s_max[0], s_max[1]), fmaxf(s_max[2], s_max[3]));
  float thresh = rowmax - 30.0f;
  #pragma unroll
  for (int i = 0; i < 32; i++) {
    if (va[i] >= thresh) { int p = atomicAdd(&s_cnt, 1); cand[p] = t + 256 * i; }
  }
  __syncthreads();
  int ncand = s_cnt;
  float bv[16]; int bi[16];
  #pragma unroll
  for (int s = 0; s < 16; s++) { bv[s] = -3.4e38f; bi[s] = 0x7fffffff; }
  for (int c = t; c < ncand; c += 256) {
    int k = cand[c];
    const float4* cb4 = (const float4*)(cb + (long)k * 768);
    float acc = 0.f;
    #pragma unroll 8
    for (int j4 = 0; j4 < 192; j4++) {
      float4 wv = cb4[j4];
      const float* xr = fs + j4 * 4;
      acc = fmaf(xr[0], wv.x, acc);
      acc = fmaf(xr[1], wv.y, acc);
      acc = fmaf(xr[2], wv.z, acc);
      acc = fmaf(xr[3], wv.w, acc);
    }
    float lg = 2.f * acc - csq[k] - 1e-5f;
    #pragma unroll
    for (int s = 0; s < 16; s++) {
      uint32_t idx = ((uint32_t)((s << 10) + n) << 13) | (uint32_t)k;
      float val = gumbel_at(idx) + lg;
      if (val > bv[s] || (val == bv[s] && k < bi[s])) { bv[s] = val; bi[s] = k; }
    }
  }
  #pragma unroll
  for (int s = 0; s < 16; s++) {
    #pragma unroll
    for (int off = 32; off >= 1; off >>= 1) {
      float ov = __shfl_xor(bv[s], off);
      int oi = __shfl_xor(bi[s], off);
      if (ov > bv[s] || (ov == bv[s] && oi < bi[s])) { bv[s] = ov; bi[s] = oi; }
    }
    if ((t & 63) == 0) { redv[s * 4 + (t >> 6)] = bv[s]; redi[s * 4 + (t >> 6)] = bi[s]; }
  }
  __syncthreads();
  if (t < 16) {
    float bvv = redv[t * 4]; int bii = redi[t * 4];
    #pragma unroll
    for (int w = 1; w < 4; w++) {
      float ov = redv[t * 4 + w]; int oi = redi[t * 4 + w];
      if (ov > bvv || (ov == bvv && oi < bii)) { bvv = ov; bii = oi; }
    }
    draws[t] = bii;
  }
  __syncthreads();
  #pragma unroll
  for (int i = 0; i < 3; i++) {
    int e = t + 256 * i;
    float ssum = 0.f;
    #pragma unroll
    for (int s = 0; s < 16; s++) ssum += cb[(long)draws[s] * 768 + e];
    float xq = ssum * 0.0625f;
    float fl = fs[e];
    out0[(long)n * 768 + e] = fl + (xq - fl);
  }
}

extern "C" void kernel_launch(void* const* d_in, const int* in_sizes, int n_in,
                              void* d_out, int out_size, void* d_ws, size_t ws_size,
                              hipStream_t stream) {
  (void)in_sizes; (void)n_in; (void)out_size; (void)ws_size;
  const float* xcq      = (const float*)d_in[0];
  const int*   amask    = (const int*)d_in[1];
  const float* fc_in_w  = (const float*)d_in[2];
  const float* fc_in_b  = (const float*)d_in[3];
  const float* fc_out_w = (const float*)d_in[4];
  const float* fc_out_b = (const float*)d_in[5];
  const float* enc_in_w = (const float*)d_in[6];
  const float* enc_in_b = (const float*)d_in[7];
  const float* enc_out_w= (const float*)d_in[8];
  const float* enc_out_b= (const float*)d_in[9];
  const float* ff1w     = (const float*)d_in[10];
  const float* ff1b     = (const float*)d_in[11];
  const float* ff2w     = (const float*)d_in[12];
  const float* ff2b     = (const float*)d_in[13];
  const float* ln1g     = (const float*)d_in[14];
  const float* ln1b     = (const float*)d_in[15];
  const float* ln2g     = (const float*)d_in[16];
  const float* ln2b     = (const float*)d_in[17];
  const float* cb       = (const float*)d_in[18];
  float* out = (float*)d_out;
  float* ws  = (float*)d_ws;

  float* x      = ws + OFF_X;
  float* qkv    = ws + OFF_QKV;
  float* attno  = ws + OFF_ATTN;
  float* flat   = ws + OFF_FLAT;
  float* csq    = ws + OFF_CSQ;
  float* approx = ws + OFF_LOGITS;
  ushort* cbbf  = (ushort*)(ws + OFF_QKV);    // overlays qkv (dead after layer 2)
  ushort* fbf   = (ushort*)(ws + OFF_ATTN);   // overlays attno (dead after layer 2)

  k_fcin<<<2048, 256, 0, stream>>>(xcq, fc_in_w, fc_in_b, x, out + 786432);
  for (int l = 0; l < 2; l++) {
    k_qkv<<<512, 64, 0, stream>>>(x, enc_in_w + l * 96 * 32, enc_in_b + l * 96, qkv);
    k_attn<<<256, 256, 0, stream>>>(qkv, amask, attno);
    k_oproj_ln<<<512, 64, 0, stream>>>(attno, enc_out_w + l * 32 * 32, enc_out_b + l * 32,
                                       ln1g + l * 32, ln1b + l * 32, x);
    k_ffn_ln<<<512, 64, 0, stream>>>(x, ff1w + l * 64 * 32, ff1b + l * 64,
                                     ff2w + l * 32 * 64, ff2b + l * 32,
                                     ln2g + l * 32, ln2b + l * 32, x);
  }
  k_fcout<<<1024, 256, 0, stream>>>(x, fc_out_w, fc_out_b, flat);
  k_cbsq<<<2048, 256, 0, stream>>>(cb, csq);
  k_tobf16<<<6144, 256, 0, stream>>>(cb, cbbf, 1572864ll);    // codebook -> bf16
  k_tobf16<<<768, 256, 0, stream>>>(flat, fbf, 196608ll);     // flat -> bf16
  k_logits_mfma<<<512, 256, 0, stream>>>(fbf, cbbf, approx);
  k_sample<<<1024, 256, 0, stream>>>(approx, cb, csq, flat, out);
}

// Round 9
// 950.278 us; speedup vs baseline: 1.3543x; 1.3543x over previous
//
#include <hip/hip_runtime.h>
#include <stdint.h>

#define NCODES 8192
#define NROWS 1024    // B*NCQ

// workspace offsets (in floats)
#define OFF_LOGITS 0ll
#define OFF_X      8388608ll
#define OFF_QKV    9437184ll
#define OFF_ATTN   12582912ll
#define OFF_FLAT   13631488ll
#define OFF_CSQ    14418944ll
// reuse: cbbf (bf16 codebook, 12 MB) overlays qkv (dead after layer 2);
//        fbf  (bf16 flat, 1.5 MB)   overlays attno (dead after layer 2);
//        approx (2*dot, fp32)       overlays logits region.

// ---------------- Threefry2x32, key = (0, 42)  (jax.random.key(42)) ----------------
__device__ __forceinline__ uint32_t rotl32(uint32_t x, int r) { return (x << r) | (x >> (32 - r)); }

__device__ __forceinline__ void tf2x32_key42(uint32_t x0, uint32_t x1, uint32_t& o0, uint32_t& o1) {
  const uint32_t k0 = 0u, k1 = 42u;
  const uint32_t k2 = k0 ^ k1 ^ 0x1BD11BDAu;
  x0 += k0; x1 += k1;
  x0 += x1; x1 = rotl32(x1,13); x1 ^= x0;
  x0 += x1; x1 = rotl32(x1,15); x1 ^= x0;
  x0 += x1; x1 = rotl32(x1,26); x1 ^= x0;
  x0 += x1; x1 = rotl32(x1, 6); x1 ^= x0;
  x0 += k1; x1 += k2 + 1u;
  x0 += x1; x1 = rotl32(x1,17); x1 ^= x0;
  x0 += x1; x1 = rotl32(x1,29); x1 ^= x0;
  x0 += x1; x1 = rotl32(x1,16); x1 ^= x0;
  x0 += x1; x1 = rotl32(x1,24); x1 ^= x0;
  x0 += k2; x1 += k0 + 2u;
  x0 += x1; x1 = rotl32(x1,13); x1 ^= x0;
  x0 += x1; x1 = rotl32(x1,15); x1 ^= x0;
  x0 += x1; x1 = rotl32(x1,26); x1 ^= x0;
  x0 += x1; x1 = rotl32(x1, 6); x1 ^= x0;
  x0 += k0; x1 += k1 + 3u;
  x0 += x1; x1 = rotl32(x1,17); x1 ^= x0;
  x0 += x1; x1 = rotl32(x1,29); x1 ^= x0;
  x0 += x1; x1 = rotl32(x1,16); x1 ^= x0;
  x0 += x1; x1 = rotl32(x1,24); x1 ^= x0;
  x0 += k1; x1 += k2 + 4u;
  x0 += x1; x1 = rotl32(x1,13); x1 ^= x0;
  x0 += x1; x1 = rotl32(x1,15); x1 ^= x0;
  x0 += x1; x1 = rotl32(x1,26); x1 ^= x0;
  x0 += x1; x1 = rotl32(x1, 6); x1 ^= x0;
  x0 += k2; x1 += k0 + 5u;
  o0 = x0; o1 = x1;
}

__device__ __forceinline__ float gumbel_at(uint32_t idx) {
  uint32_t y0, y1;
  tf2x32_key42(0u, idx, y0, y1);
  uint32_t bits = y0 ^ y1;
  float f = __uint_as_float((bits >> 9) | 0x3f800000u) - 1.0f;
  float u = fmaxf(f, 1.17549435e-38f);
  return -logf(-logf(u));
}

// ---------------- K0a: plain strided float4 copy xcq -> out (output 1) ----------------
__global__ __launch_bounds__(256) void k_copy(const float* __restrict__ src,
                                              float* __restrict__ dst) {
  long T = (long)blockIdx.x * 256 + threadIdx.x;
  const float4* s4 = (const float4*)src;
  float4* d4 = (float4*)dst;
  #pragma unroll
  for (int i = 0; i < 12; i++) d4[T + (long)i * 524288] = s4[T + (long)i * 524288];
}

// ---------------- K0b: x = xcq @ fc_in_w.T + b  (GEMM only, no copy) ------------------
// 64 tokens/block, lane=token, wave w -> cols 8w..8w+7. W reads wave-uniform ->
// s_loads (zero W vector traffic; acc[8] keeps VGPR low, no spill).
// Reg-staged double-buffered LDS, loads for chunk k+1 issued before the barrier of
// chunk k (T14); plain __syncthreads only — no inline asm, no global_load_lds.
// Contraction order identical to rounds 1-2 (chunks ascending, j4 0..7) -> x bit-identical.
__global__ __launch_bounds__(256) void k_fcin(const float* __restrict__ xcq,
                                              const float* __restrict__ W,
                                              const float* __restrict__ b,
                                              float* __restrict__ x) {
  __shared__ __align__(16) float xs[2][64 * 36];   // 18.4 KB, +36 stride (round-0 proven)
  int t = threadIdx.x;
  int w = t >> 6, lane = t & 63;
  int wu = __builtin_amdgcn_readfirstlane(w);      // provably wave-uniform -> W s_loads
  long tb = (long)blockIdx.x * 64;
  const float4* xcq4 = (const float4*)xcq;
  const float4* W4 = (const float4*)W;
  float acc[8];
  #pragma unroll
  for (int i = 0; i < 8; i++) acc[i] = 0.f;

#define LOADR(R, kt)                                             \
  { _Pragma("unroll")                                            \
    for (int p = 0; p < 2; p++) {                                \
      int f = t + 256 * p;                                       \
      int row = f >> 3, j4 = f & 7;                              \
      R[p] = xcq4[(tb + row) * 192 + (kt) * 8 + j4];             \
    } }
#define STORELDS(R, buf)                                         \
  { _Pragma("unroll")                                            \
    for (int p = 0; p < 2; p++) {                                \
      int f = t + 256 * p;                                       \
      int row = f >> 3, j4 = f & 7;                              \
      *(float4*)(xs[buf] + row * 36 + j4 * 4) = R[p];            \
    } }
#define COMP(kt, buf)                                            \
  { _Pragma("unroll")                                            \
    for (int j4 = 0; j4 < 8; j4++) {                             \
      float4 xv = *(const float4*)(xs[buf] + lane * 36 + j4 * 4);\
      _Pragma("unroll")                                          \
      for (int ci = 0; ci < 8; ci++) {                           \
        float4 wv = W4[(wu * 8 + ci) * 192 + (kt) * 8 + j4];     \
        acc[ci] += xv.x*wv.x + xv.y*wv.y + xv.z*wv.z + xv.w*wv.w;\
      } } }

  float4 rA[2], rB[2];
  LOADR(rA, 0);
  #pragma unroll 1
  for (int kt = 0; kt < 24; kt += 2) {
    STORELDS(rA, 0);                       // implicit vmcnt wait for rA only
    if (kt + 1 < 24) LOADR(rB, kt + 1);    // issue-early (T14)
    __syncthreads();
    COMP(kt, 0);
    STORELDS(rB, 1);
    if (kt + 2 < 24) LOADR(rA, kt + 2);
    __syncthreads();
    COMP(kt + 1, 1);
  }
#undef LOADR
#undef STORELDS
#undef COMP
  __syncthreads();
  // transpose through LDS for coalesced x write (stride 36 kills write conflicts)
  float* xsf = xs[0];
  *(float4*)(xsf + lane * 36 + w * 8)     = make_float4(acc[0] + b[w*8+0], acc[1] + b[w*8+1], acc[2] + b[w*8+2], acc[3] + b[w*8+3]);
  *(float4*)(xsf + lane * 36 + w * 8 + 4) = make_float4(acc[4] + b[w*8+4], acc[5] + b[w*8+5], acc[6] + b[w*8+6], acc[7] + b[w*8+7]);
  __syncthreads();
  float4* x4 = (float4*)x;
  #pragma unroll
  for (int p = 0; p < 2; p++) {
    int f = t + 256 * p;
    int row = f >> 3, c4 = f & 7;
    x4[(tb + row) * 8 + c4] = *(const float4*)(xsf + row * 36 + c4 * 4);
  }
}

// ---------------- K1: qkv = x @ Win.T + bin  (per-token, W wave-uniform) ----------------
__global__ __launch_bounds__(64) void k_qkv(const float* __restrict__ x,
                                            const float* __restrict__ W,
                                            const float* __restrict__ b,
                                            float* __restrict__ qkv) {
  long token = (long)blockIdx.x * 64 + threadIdx.x;
  const float4* x4 = (const float4*)x;
  const float4* W4 = (const float4*)W;
  float4* q4 = (float4*)qkv;
  float4 xr[8];
  #pragma unroll
  for (int j4 = 0; j4 < 8; j4++) xr[j4] = x4[token * 8 + j4];
  #pragma unroll
  for (int c4 = 0; c4 < 24; c4++) {
    float s[4];
    #pragma unroll
    for (int q = 0; q < 4; q++) {
      int c = c4 * 4 + q;
      float acc = 0.f;
      #pragma unroll
      for (int j4 = 0; j4 < 8; j4++) {
        float4 wv = W4[c * 8 + j4];   // uniform
        acc += xr[j4].x * wv.x + xr[j4].y * wv.y + xr[j4].z * wv.z + xr[j4].w * wv.w;
      }
      s[q] = acc + b[c];
    }
    q4[token * 24 + c4] = make_float4(s[0], s[1], s[2], s[3]);
  }
}

// ---------------- K2: attention, one (batch, head) per block, 2 queries/thread ----------
__global__ __launch_bounds__(256) void k_attn(const float* __restrict__ qkv,
                                              const int* __restrict__ amask,
                                              float* __restrict__ attno) {
  int z = blockIdx.x;              // 0..255
  int b = z >> 2;
  int h = z & 3;
  __shared__ float4 ks4[512 * 2];
  __shared__ float4 vs4[512 * 2];
  __shared__ float inval[512];
  int t = threadIdx.x;
  long qb4 = (long)b * 512 * 24;
  const float4* qkv4 = (const float4*)qkv;
  #pragma unroll
  for (int p = 0; p < 4; p++) {
    int f = t + 256 * p;             // token*2 + half4
    int tok = f >> 1, hf = f & 1;
    ks4[f] = qkv4[qb4 + (long)tok * 24 + 8 + h * 2 + hf];
    vs4[f] = qkv4[qb4 + (long)tok * 24 + 16 + h * 2 + hf];
  }
  #pragma unroll
  for (int p = 0; p < 2; p++) {
    int l = t + 256 * p;
    inval[l] = (l < 16 || amask[b * 496 + (l - 16)] != 0) ? 0.f : 1.f;
  }
  __syncthreads();
  const float scale = 0.35355339059327373f;
  float4 qa0 = qkv4[qb4 + (long)t * 24 + h * 2];
  float4 qb0 = qkv4[qb4 + (long)t * 24 + h * 2 + 1];
  float4 qa1 = qkv4[qb4 + (long)(t + 256) * 24 + h * 2];
  float4 qb1 = qkv4[qb4 + (long)(t + 256) * 24 + h * 2 + 1];
  float m0 = -3.4e38f, m1 = -3.4e38f;
  #pragma unroll 2
  for (int lk = 0; lk < 512; lk++) {
    float4 ka = ks4[lk * 2], kb = ks4[lk * 2 + 1];
    float iv = inval[lk];
    float s0 = qa0.x*ka.x + qa0.y*ka.y + qa0.z*ka.z + qa0.w*ka.w
             + qb0.x*kb.x + qb0.y*kb.y + qb0.z*kb.z + qb0.w*kb.w;
    s0 *= scale;
    s0 = iv != 0.f ? -1e9f : s0;
    m0 = fmaxf(m0, s0);
    float s1 = qa1.x*ka.x + qa1.y*ka.y + qa1.z*ka.z + qa1.w*ka.w
             + qb1.x*kb.x + qb1.y*kb.y + qb1.z*kb.z + qb1.w*kb.w;
    s1 *= scale;
    s1 = iv != 0.f ? -1e9f : s1;
    m1 = fmaxf(m1, s1);
  }
  float d0 = 0.f, d1 = 0.f;
  float4 o00 = make_float4(0,0,0,0), o01 = make_float4(0,0,0,0);
  float4 o10 = make_float4(0,0,0,0), o11 = make_float4(0,0,0,0);
  #pragma unroll 2
  for (int lk = 0; lk < 512; lk++) {
    float4 ka = ks4[lk * 2], kb = ks4[lk * 2 + 1];
    float4 va = vs4[lk * 2], vb = vs4[lk * 2 + 1];
    float iv = inval[lk];
    float s0 = qa0.x*ka.x + qa0.y*ka.y + qa0.z*ka.z + qa0.w*ka.w
             + qb0.x*kb.x + qb0.y*kb.y + qb0.z*kb.z + qb0.w*kb.w;
    s0 *= scale;
    s0 = iv != 0.f ? -1e9f : s0;
    float p0 = expf(s0 - m0);
    d0 += p0;
    o00.x += p0 * va.x; o00.y += p0 * va.y; o00.z += p0 * va.z; o00.w += p0 * va.w;
    o01.x += p0 * vb.x; o01.y += p0 * vb.y; o01.z += p0 * vb.z; o01.w += p0 * vb.w;
    float s1 = qa1.x*ka.x + qa1.y*ka.y + qa1.z*ka.z + qa1.w*ka.w
             + qb1.x*kb.x + qb1.y*kb.y + qb1.z*kb.z + qb1.w*kb.w;
    s1 *= scale;
    s1 = iv != 0.f ? -1e9f : s1;
    float p1 = expf(s1 - m1);
    d1 += p1;
    o10.x += p1 * va.x; o10.y += p1 * va.y; o10.z += p1 * va.z; o10.w += p1 * va.w;
    o11.x += p1 * vb.x; o11.y += p1 * vb.y; o11.z += p1 * vb.z; o11.w += p1 * vb.w;
  }
  float4* a4 = (float4*)attno;
  float inv0 = 1.f / d0;
  long ob0 = ((long)b * 512 + t) * 8 + h * 2;
  a4[ob0]     = make_float4(o00.x*inv0, o00.y*inv0, o00.z*inv0, o00.w*inv0);
  a4[ob0 + 1] = make_float4(o01.x*inv0, o01.y*inv0, o01.z*inv0, o01.w*inv0);
  float inv1 = 1.f / d1;
  long ob1 = ((long)b * 512 + t + 256) * 8 + h * 2;
  a4[ob1]     = make_float4(o10.x*inv1, o10.y*inv1, o10.z*inv1, o10.w*inv1);
  a4[ob1 + 1] = make_float4(o11.x*inv1, o11.y*inv1, o11.z*inv1, o11.w*inv1);
}

// ---------------- K3: x = LN1(x + attno @ Wout.T + bout)  (per-token) ----------------
__global__ __launch_bounds__(64) void k_oproj_ln(const float* __restrict__ attno,
                                                 const float* __restrict__ W,
                                                 const float* __restrict__ b,
                                                 const float* __restrict__ g,
                                                 const float* __restrict__ beta,
                                                 float* __restrict__ x) {
  long token = (long)blockIdx.x * 64 + threadIdx.x;
  const float4* a4 = (const float4*)attno;
  const float4* x4 = (const float4*)x;
  const float4* W4 = (const float4*)W;
  float4 orow[8];
  float xr[32];
  #pragma unroll
  for (int j4 = 0; j4 < 8; j4++) {
    orow[j4] = a4[token * 8 + j4];
    float4 v = x4[token * 8 + j4];
    xr[j4*4] = v.x; xr[j4*4+1] = v.y; xr[j4*4+2] = v.z; xr[j4*4+3] = v.w;
  }
  float v[32];
  #pragma unroll
  for (int c = 0; c < 32; c++) {
    float acc = 0.f;
    #pragma unroll
    for (int j4 = 0; j4 < 8; j4++) {
      float4 wv = W4[c * 8 + j4];   // uniform
      acc += orow[j4].x * wv.x + orow[j4].y * wv.y + orow[j4].z * wv.z + orow[j4].w * wv.w;
    }
    v[c] = acc + b[c] + xr[c];
  }
  float mu = 0.f;
  #pragma unroll
  for (int c = 0; c < 32; c++) mu += v[c];
  mu *= 0.03125f;
  float var = 0.f;
  #pragma unroll
  for (int c = 0; c < 32; c++) { float d = v[c] - mu; var += d * d; }
  var *= 0.03125f;
  float inv = 1.f / sqrtf(var + 1e-5f);
  float4* xo4 = (float4*)x;
  #pragma unroll
  for (int j4 = 0; j4 < 8; j4++) {
    float4 o;
    o.x = g[j4*4]   * (v[j4*4]   - mu) * inv + beta[j4*4];
    o.y = g[j4*4+1] * (v[j4*4+1] - mu) * inv + beta[j4*4+1];
    o.z = g[j4*4+2] * (v[j4*4+2] - mu) * inv + beta[j4*4+2];
    o.w = g[j4*4+3] * (v[j4*4+3] - mu) * inv + beta[j4*4+3];
    xo4[token * 8 + j4] = o;
  }
}

// ---------------- K4: x = LN2(x + relu(x@W1.T+b1)@W2.T + b2)  (per-token) ----------------
__global__ __launch_bounds__(64) void k_ffn_ln(const float* __restrict__ x,
                                               const float* __restrict__ W1,
                                               const float* __restrict__ b1,
                                               const float* __restrict__ W2,
                                               const float* __restrict__ b2,
                                               const float* __restrict__ g,
                                               const float* __restrict__ beta,
                                               float* __restrict__ xout) {
  long token = (long)blockIdx.x * 64 + threadIdx.x;
  const float4* x4 = (const float4*)x;
  const float4* W14 = (const float4*)W1;
  const float4* W24 = (const float4*)W2;
  float xr[32];
  #pragma unroll
  for (int j4 = 0; j4 < 8; j4++) {
    float4 v = x4[token * 8 + j4];
    xr[j4*4] = v.x; xr[j4*4+1] = v.y; xr[j4*4+2] = v.z; xr[j4*4+3] = v.w;
  }
  float h[64];
  #pragma unroll
  for (int c = 0; c < 64; c++) {
    float acc = 0.f;
    #pragma unroll
    for (int j4 = 0; j4 < 8; j4++) {
      float4 wv = W14[c * 8 + j4];   // uniform
      acc += xr[j4*4] * wv.x + xr[j4*4+1] * wv.y + xr[j4*4+2] * wv.z + xr[j4*4+3] * wv.w;
    }
    h[c] = fmaxf(acc + b1[c], 0.f);
  }
  float v[32];
  #pragma unroll
  for (int c = 0; c < 32; c++) {
    float acc = 0.f;
    #pragma unroll
    for (int j4 = 0; j4 < 16; j4++) {
      float4 wv = W24[c * 16 + j4];   // uniform
      acc += h[j4*4] * wv.x + h[j4*4+1] * wv.y + h[j4*4+2] * wv.z + h[j4*4+3] * wv.w;
    }
    v[c] = acc + b2[c] + xr[c];
  }
  float mu = 0.f;
  #pragma unroll
  for (int c = 0; c < 32; c++) mu += v[c];
  mu *= 0.03125f;
  float var = 0.f;
  #pragma unroll
  for (int c = 0; c < 32; c++) { float d = v[c] - mu; var += d * d; }
  var *= 0.03125f;
  float inv = 1.f / sqrtf(var + 1e-5f);
  float4* xo4 = (float4*)xout;
  #pragma unroll
  for (int j4 = 0; j4 < 8; j4++) {
    float4 o;
    o.x = g[j4*4]   * (v[j4*4]   - mu) * inv + beta[j4*4];
    o.y = g[j4*4+1] * (v[j4*4+1] - mu) * inv + beta[j4*4+1];
    o.z = g[j4*4+2] * (v[j4*4+2] - mu) * inv + beta[j4*4+2];
    o.w = g[j4*4+3] * (v[j4*4+3] - mu) * inv + beta[j4*4+3];
    xo4[token * 8 + j4] = o;
  }
}

// ---------------- K5: flat = x[:, :16] @ fc_out_w.T + b  (one flat row per block) -------
__global__ __launch_bounds__(256) void k_fcout(const float* __restrict__ x,
                                               const float* __restrict__ W,
                                               const float* __restrict__ b,
                                               float* __restrict__ flat) {
  int n = blockIdx.x;           // 0..1023 flat row
  int bb = n >> 4, r = n & 15;
  long xrow = (long)bb * 512 + r;
  const float4* x4 = (const float4*)x;
  float4 xr[8];
  #pragma unroll
  for (int j4 = 0; j4 < 8; j4++) xr[j4] = x4[xrow * 8 + j4];   // uniform -> s_load
  int t = threadIdx.x;
  #pragma unroll
  for (int i = 0; i < 3; i++) {
    int e = t + 256 * i;
    const float4* w4 = (const float4*)(W + e * 32);
    float s = 0.f;
    #pragma unroll
    for (int j4 = 0; j4 < 8; j4++) {
      float4 wv = w4[j4];
      s += xr[j4].x * wv.x + xr[j4].y * wv.y + xr[j4].z * wv.z + xr[j4].w * wv.w;
    }
    flat[(long)n * 768 + e] = s + b[e];
  }
}

// ---------------- K6: cb_sq[k] = sum(codebook[k]^2) ----------------
__global__ __launch_bounds__(256) void k_cbsq(const float* __restrict__ cb,
                                              float* __restrict__ cb_sq) {
  int w = threadIdx.x >> 6, lane = threadIdx.x & 63;
  int k = blockIdx.x * 4 + w;
  const float* row = cb + (long)k * 768;
  float s = 0.f;
  #pragma unroll
  for (int i = 0; i < 12; i++) { float v = row[lane + 64 * i]; s += v * v; }
  #pragma unroll
  for (int off = 32; off >= 1; off >>= 1) s += __shfl_xor(s, off);
  if (lane == 0) cb_sq[k] = s;
}

// ---------------- K6b: fp32 -> bf16 (RNE), vectorized float4 -> ushort4 --------------
__device__ __forceinline__ ushort f2bf(float x) {
  uint32_t u = __float_as_uint(x);
  uint32_t r = (u + 0x7fffu + ((u >> 16) & 1u)) >> 16;
  return (ushort)r;
}

__global__ __launch_bounds__(256) void k_tobf16(const float* __restrict__ src,
                                                ushort* __restrict__ dst, long n4) {
  long i = (long)blockIdx.x * 256 + threadIdx.x;
  if (i >= n4) return;
  float4 v = ((const float4*)src)[i];
  ushort4 o;
  o.x = f2bf(v.x); o.y = f2bf(v.y); o.z = f2bf(v.z); o.w = f2bf(v.w);
  ((ushort4*)dst)[i] = o;
}

// ---------------- K7: approx[n,k] = 2 * <flat_bf16[n], cb_bf16[k]>  via MFMA ----------
typedef __attribute__((ext_vector_type(8))) short bf16x8;
typedef __attribute__((ext_vector_type(4))) float f32x4;

__global__ __launch_bounds__(256, 2) void k_logits_mfma(const ushort* __restrict__ fbf,
                                                        const ushort* __restrict__ cbbf,
                                                        float* __restrict__ approx) {
  __shared__ __align__(16) short As[128 * 64];
  __shared__ __align__(16) short Bs[128 * 64];
  int t = threadIdx.x;
  int mb = blockIdx.x & 7;        // 8 row-blocks of 128 (M=1024)
  int nb = blockIdx.x >> 3;       // 64 col-blocks of 128 (N=8192)
  int w = t >> 6, lane = t & 63;
  int wr = w >> 1, wc = w & 1;    // 2x2 wave grid, 64x64 per wave

  f32x4 zero; zero.x = 0.f; zero.y = 0.f; zero.z = 0.f; zero.w = 0.f;
  f32x4 acc[4][4];
  #pragma unroll
  for (int i = 0; i < 4; i++)
    #pragma unroll
    for (int j = 0; j < 4; j++) acc[i][j] = zero;

  for (int kt = 0; kt < 12; kt++) {
    int kc = kt * 64;
    bf16x8 ra[4], rb[4];
    #pragma unroll
    for (int p = 0; p < 4; p++) {
      int li = p * 256 + t;
      int row = li >> 3, s = li & 7;
      ra[p] = *(const bf16x8*)(fbf + (long)(mb * 128 + row) * 768 + kc + s * 8);
      rb[p] = *(const bf16x8*)(cbbf + (long)(nb * 128 + row) * 768 + kc + s * 8);
    }
    __syncthreads();
    #pragma unroll
    for (int p = 0; p < 4; p++) {
      int li = p * 256 + t;
      int row = li >> 3, s = li & 7, ss = s ^ (row & 7);
      *(bf16x8*)(As + row * 64 + ss * 8) = ra[p];
      *(bf16x8*)(Bs + row * 64 + ss * 8) = rb[p];
    }
    __syncthreads();
    #pragma unroll
    for (int ks = 0; ks < 2; ks++) {
      int slot = ks * 4 + (lane >> 4);
      bf16x8 a[4], b[4];
      #pragma unroll
      for (int i = 0; i < 4; i++) {
        int rowa = wr * 64 + i * 16 + (lane & 15);
        a[i] = *(const bf16x8*)(As + rowa * 64 + (slot ^ (rowa & 7)) * 8);
        int rowb = wc * 64 + i * 16 + (lane & 15);
        b[i] = *(const bf16x8*)(Bs + rowb * 64 + (slot ^ (rowb & 7)) * 8);
      }
      #pragma unroll
      for (int i = 0; i < 4; i++)
        #pragma unroll
        for (int j = 0; j < 4; j++)
          acc[i][j] = __builtin_amdgcn_mfma_f32_16x16x32_bf16(a[i], b[j], acc[i][j], 0, 0, 0);
    }
  }
  long rbase = (long)mb * 128 + wr * 64 + (lane >> 4) * 4;
  int cbase = nb * 128 + wc * 64 + (lane & 15);
  #pragma unroll
  for (int i = 0; i < 4; i++) {
    #pragma unroll
    for (int j = 0; j < 4; j++) {
      f32x4 v = acc[i][j];
      long r0 = rbase + i * 16;
      int c = cbase + j * 16;
      approx[(r0 + 0) * 8192 + c] = 2.f * v.x;
      approx[(r0 + 1) * 8192 + c] = 2.f * v.y;
      approx[(r0 + 2) * 8192 + c] = 2.f * v.z;
      approx[(r0 + 3) * 8192 + c] = 2.f * v.w;
    }
  }
}

// ---------------- K8: gumbel-max sampling with approx-threshold + exact rescue --------
__global__ __launch_bounds__(256) void k_sample(const float* __restrict__ approx,
                                                const float* __restrict__ cb,
                                                const float* __restrict__ csq,
                                                const float* __restrict__ flat,
                                                float* __restrict__ out0) {
  int n = blockIdx.x, t = threadIdx.x;
  const float* arow = approx + (long)n * 8192;
  __shared__ float s_max[4];
  __shared__ int s_cnt;
  __shared__ int cand[8192];
  __shared__ float fs[768];
  __shared__ float redv[64];
  __shared__ int redi[64];
  __shared__ int draws[16];
  if (t < 192) ((float4*)fs)[t] = ((const float4*)(flat + (long)n * 768))[t];
  float va[32];
  float m = -3.4e38f;
  #pragma unroll
  for (int i = 0; i < 32; i++) { va[i] = arow[t + 256 * i]; m = fmaxf(m, va[i]); }
  #pragma unroll
  for (int off = 32; off >= 1; off >>= 1) m = fmaxf(m, __shfl_xor(m, off));
  if ((t & 63) == 0) s_max[t >> 6] = m;
  if (t == 0) s_cnt = 0;
  __syncthreads();
  float rowmax = fmaxf(fmaxf(s_max[0], s_max[1]), fmaxf(s_max[2], s_max[3]));
  float thresh = rowmax - 30.0f;
  #pragma unroll
  for (int i = 0; i < 32; i++) {
    if (va[i] >= thresh) { int p = atomicAdd(&s_cnt, 1); cand[p] = t + 256 * i; }
  }
  __syncthreads();
  int ncand = s_cnt;
  float bv[16]; int bi[16];
  #pragma unroll
  for (int s = 0; s < 16; s++) { bv[s] = -3.4e38f; bi[s] = 0x7fffffff; }
  for (int c = t; c < ncand; c += 256) {
    int k = cand[c];
    const float4* cb4 = (const float4*)(cb + (long)k * 768);
    float acc = 0.f;
    #pragma unroll 8
    for (int j4 = 0; j4 < 192; j4++) {
      float4 wv = cb4[j4];
      const float* xr = fs + j4 * 4;
      acc = fmaf(xr[0], wv.x, acc);
      acc = fmaf(xr[1], wv.y, acc);
      acc = fmaf(xr[2], wv.z, acc);
      acc = fmaf(xr[3], wv.w, acc);
    }
    float lg = 2.f * acc - csq[k] - 1e-5f;
    #pragma unroll
    for (int s = 0; s < 16; s++) {
      uint32_t idx = ((uint32_t)((s << 10) + n) << 13) | (uint32_t)k;
      float val = gumbel_at(idx) + lg;
      if (val > bv[s] || (val == bv[s] && k < bi[s])) { bv[s] = val; bi[s] = k; }
    }
  }
  #pragma unroll
  for (int s = 0; s < 16; s++) {
    #pragma unroll
    for (int off = 32; off >= 1; off >>= 1) {
      float ov = __shfl_xor(bv[s], off);
      int oi = __shfl_xor(bi[s], off);
      if (ov > bv[s] || (ov == bv[s] && oi < bi[s])) { bv[s] = ov; bi[s] = oi; }
    }
    if ((t & 63) == 0) { redv[s * 4 + (t >> 6)] = bv[s]; redi[s * 4 + (t >> 6)] = bi[s]; }
  }
  __syncthreads();
  if (t < 16) {
    float bvv = redv[t * 4]; int bii = redi[t * 4];
    #pragma unroll
    for (int w = 1; w < 4; w++) {
      float ov = redv[t * 4 + w]; int oi = redi[t * 4 + w];
      if (ov > bvv || (ov == bvv && oi < bii)) { bvv = ov; bii = oi; }
    }
    draws[t] = bii;
  }
  __syncthreads();
  #pragma unroll
  for (int i = 0; i < 3; i++) {
    int e = t + 256 * i;
    float ssum = 0.f;
    #pragma unroll
    for (int s = 0; s < 16; s++) ssum += cb[(long)draws[s] * 768 + e];
    float xq = ssum * 0.0625f;
    float fl = fs[e];
    out0[(long)n * 768 + e] = fl + (xq - fl);
  }
}

extern "C" void kernel_launch(void* const* d_in, const int* in_sizes, int n_in,
                              void* d_out, int out_size, void* d_ws, size_t ws_size,
                              hipStream_t stream) {
  (void)in_sizes; (void)n_in; (void)out_size; (void)ws_size;
  const float* xcq      = (const float*)d_in[0];
  const int*   amask    = (const int*)d_in[1];
  const float* fc_in_w  = (const float*)d_in[2];
  const float* fc_in_b  = (const float*)d_in[3];
  const float* fc_out_w = (const float*)d_in[4];
  const float* fc_out_b = (const float*)d_in[5];
  const float* enc_in_w = (const float*)d_in[6];
  const float* enc_in_b = (const float*)d_in[7];
  const float* enc_out_w= (const float*)d_in[8];
  const float* enc_out_b= (const float*)d_in[9];
  const float* ff1w     = (const float*)d_in[10];
  const float* ff1b     = (const float*)d_in[11];
  const float* ff2w     = (const float*)d_in[12];
  const float* ff2b     = (const float*)d_in[13];
  const float* ln1g     = (const float*)d_in[14];
  const float* ln1b     = (const float*)d_in[15];
  const float* ln2g     = (const float*)d_in[16];
  const float* ln2b     = (const float*)d_in[17];
  const float* cb       = (const float*)d_in[18];
  float* out = (float*)d_out;
  float* ws  = (float*)d_ws;

  float* x      = ws + OFF_X;
  float* qkv    = ws + OFF_QKV;
  float* attno  = ws + OFF_ATTN;
  float* flat   = ws + OFF_FLAT;
  float* csq    = ws + OFF_CSQ;
  float* approx = ws + OFF_LOGITS;
  ushort* cbbf  = (ushort*)(ws + OFF_QKV);    // overlays qkv (dead after layer 2)
  ushort* fbf   = (ushort*)(ws + OFF_ATTN);   // overlays attno (dead after layer 2)

  k_fcin<<<512, 256, 0, stream>>>(xcq, fc_in_w, fc_in_b, x);
  k_copy<<<2048, 256, 0, stream>>>(xcq, out + 786432);
  for (int l = 0; l < 2; l++) {
    k_qkv<<<512, 64, 0, stream>>>(x, enc_in_w + l * 96 * 32, enc_in_b + l * 96, qkv);
    k_attn<<<256, 256, 0, stream>>>(qkv, amask, attno);
    k_oproj_ln<<<512, 64, 0, stream>>>(attno, enc_out_w + l * 32 * 32, enc_out_b + l * 32,
                                       ln1g + l * 32, ln1b + l * 32, x);
    k_ffn_ln<<<512, 64, 0, stream>>>(x, ff1w + l * 64 * 32, ff1b + l * 64,
                                     ff2w + l * 32 * 64, ff2b + l * 32,
                                     ln2g + l * 32, ln2b + l * 32, x);
  }
  k_fcout<<<1024, 256, 0, stream>>>(x, fc_out_w, fc_out_b, flat);
  k_cbsq<<<2048, 256, 0, stream>>>(cb, csq);
  k_tobf16<<<6144, 256, 0, stream>>>(cb, cbbf, 1572864ll);    // codebook -> bf16
  k_tobf16<<<768, 256, 0, stream>>>(flat, fbf, 196608ll);     // flat -> bf16
  k_logits_mfma<<<512, 256, 0, stream>>>(fbf, cbbf, approx);
  k_sample<<<1024, 256, 0, stream>>>(approx, cb, csq, flat, out);
}